// Round 1
// baseline (572.615 us; speedup 1.0000x reference)
//
#include <hip/hip_runtime.h>

// TopK-mask: per row of [16384, 4096] f32, keep the 64 largest values, zero the rest.
// One 256-thread block per row. Keys = order-preserving uint32 transform of f32.
// 3-pass radix select (12+12+8 bits) over a 4096-bin LDS histogram, then masked write.
// Ties at the K-th value are broken by lowest index (matches jax.lax.top_k).

#define COLS 4096
#define KTOP 64u
#define NT 256
#define EPT 16   // elements per thread (COLS / NT)

__global__ __launch_bounds__(NT) void topk_mask_kernel(const float* __restrict__ x,
                                                       float* __restrict__ out) {
    const int row = blockIdx.x;
    const int t = threadIdx.x;
    const float* __restrict__ xr = x + (size_t)row * COLS;
    float* __restrict__ orow = out + (size_t)row * COLS;

    __shared__ unsigned hist[4096];   // 16 KB
    __shared__ unsigned sc[NT];
    __shared__ unsigned sc2[NT];
    __shared__ unsigned sh_selbin;
    __shared__ unsigned sh_selS;

    // ---- Load 16 contiguous floats per thread; convert to sortable keys ----
    // key order == float order: larger key <=> larger float.
    unsigned key[EPT];
    const float4* xv = reinterpret_cast<const float4*>(xr) + t * 4;
    #pragma unroll
    for (int c = 0; c < 4; ++c) {
        float4 v = xv[c];
        float f[4] = {v.x, v.y, v.z, v.w};
        #pragma unroll
        for (int j = 0; j < 4; ++j) {
            unsigned u = __float_as_uint(f[j]);
            key[4 * c + j] = (u & 0x80000000u) ? ~u : (u | 0x80000000u);
        }
    }

    unsigned prefix = 0;   // accumulated selected high bits
    unsigned need = KTOP;  // how many still to take within the current prefix set
    unsigned T = 0;        // final threshold key (value of the K-th largest)

    // ---- 3-pass radix select: digits of 12, 12, 8 bits (MSB first) ----
    for (int pass = 0; pass < 3; ++pass) {
        // zero histogram (coalesced)
        #pragma unroll
        for (int i = 0; i < 16; ++i) hist[t + NT * i] = 0u;
        __syncthreads();

        const int binshift = (pass == 0) ? 20 : (pass == 1 ? 8 : 0);
        const unsigned binmask = (pass == 2) ? 0xFFu : 0xFFFu;

        #pragma unroll
        for (int j = 0; j < EPT; ++j) {
            unsigned k = key[j];
            bool part;
            if (pass == 0)      part = true;
            else if (pass == 1) part = ((k >> 20) == prefix);
            else                part = ((k >> 8)  == prefix);
            if (part) atomicAdd(&hist[(k >> binshift) & binmask], 1u);
        }
        __syncthreads();

        // per-thread partial sums over its 16 bins [16t, 16t+16)
        unsigned L = 0;
        const int bb = t * 16;
        #pragma unroll
        for (int i = 0; i < 16; ++i) L += hist[bb + i];
        sc[t] = L;
        __syncthreads();

        // wave 0: exclusive SUFFIX scan over the 256 partial sums (no barriers inside)
        if (t < 64) {
            unsigned a0 = sc[4 * t + 0], a1 = sc[4 * t + 1];
            unsigned a2 = sc[4 * t + 2], a3 = sc[4 * t + 3];
            unsigned tot = a0 + a1 + a2 + a3;
            unsigned suf = tot;
            #pragma unroll
            for (int d = 1; d < 64; d <<= 1) {
                unsigned o = __shfl_down(suf, d, 64);
                if (t + d < 64) suf += o;
            }
            unsigned e = suf - tot;   // sum of entries > 4t+3
            sc2[4 * t + 3] = e;
            e += a3; sc2[4 * t + 2] = e;
            e += a2; sc2[4 * t + 1] = e;
            e += a1; sc2[4 * t + 0] = e;
        }
        __syncthreads();

        // walk own bins high->low; exactly one (bin) satisfies S < need <= S+h
        unsigned S = sc2[t];
        #pragma unroll
        for (int i = 15; i >= 0; --i) {
            unsigned h = hist[bb + i];
            unsigned Sn = S + h;
            if (S < need && need <= Sn) { sh_selbin = (unsigned)(bb + i); sh_selS = S; }
            S = Sn;
        }
        __syncthreads();

        unsigned b = sh_selbin;
        need -= sh_selS;  // uniform update (sh_selS uniform)
        if (pass == 0)      prefix = b;
        else if (pass == 1) prefix = (prefix << 12) | b;
        else                T = (prefix << 8) | b;
        __syncthreads();  // protect hist reads above from next pass's zeroing
    }

    // ---- Stable rank among key==T elements, ascending index order ----
    // Thread t owns contiguous positions [16t, 16t+16) => index order == (t, j) order.
    unsigned eq = 0;
    #pragma unroll
    for (int j = 0; j < EPT; ++j) eq += (key[j] == T) ? 1u : 0u;
    sc[t] = eq;
    __syncthreads();
    if (t < 64) {
        unsigned a0 = sc[4 * t + 0], a1 = sc[4 * t + 1];
        unsigned a2 = sc[4 * t + 2], a3 = sc[4 * t + 3];
        unsigned tot = a0 + a1 + a2 + a3;
        unsigned pre = tot;
        #pragma unroll
        for (int d = 1; d < 64; d <<= 1) {
            unsigned o = __shfl_up(pre, d, 64);
            if (t >= d) pre += o;
        }
        unsigned e = pre - tot;   // sum of entries < 4t
        sc2[4 * t + 0] = e;
        e += a0; sc2[4 * t + 1] = e;
        e += a1; sc2[4 * t + 2] = e;
        e += a2; sc2[4 * t + 3] = e;
    }
    __syncthreads();

    // ---- Output: keep key>T always; key==T only for the first `need` by index ----
    unsigned rank = sc2[t];
    float4* ov = reinterpret_cast<float4*>(orow) + t * 4;
    #pragma unroll
    for (int c = 0; c < 4; ++c) {
        float r[4];
        #pragma unroll
        for (int j = 0; j < 4; ++j) {
            unsigned k = key[4 * c + j];
            bool inc;
            if (k > T)       inc = true;
            else if (k == T) { inc = (rank < need); rank += 1u; }
            else             inc = false;
            unsigned u = (k & 0x80000000u) ? (k ^ 0x80000000u) : ~k;  // inverse transform
            r[j] = inc ? __uint_as_float(u) : 0.0f;
        }
        float4 o4;
        o4.x = r[0]; o4.y = r[1]; o4.z = r[2]; o4.w = r[3];
        ov[c] = o4;
    }
}

extern "C" void kernel_launch(void* const* d_in, const int* in_sizes, int n_in,
                              void* d_out, int out_size, void* d_ws, size_t ws_size,
                              hipStream_t stream) {
    const float* x = (const float*)d_in[0];
    float* out = (float*)d_out;
    const int rows = in_sizes[0] / COLS;  // 16384
    topk_mask_kernel<<<rows, NT, 0, stream>>>(x, out);
}

// Round 2
// 439.073 us; speedup vs baseline: 1.3041x; 1.3041x over previous
//
#include <hip/hip_runtime.h>

// TopK-mask: per row of [16384, 4096] f32, keep the 64 largest values, zero the rest.
// One 256-thread block per row. Keys = order-preserving uint32 transform of f32.
// Radix select over digits 12+10+10 (MSB first) with LDS histograms
// (4096 bins pass 0, 1024 bins passes 1-2), then masked vectorized write.
// Ties at the K-th value: lowest index wins (matches jax.lax.top_k).
//
// LDS layout note: hist is PADDED — phys(b) = b + (b>>4) — so thread t's 16
// contiguous pass-0 bins sit at base 17*t: stride 17 is odd -> banks bijective
// mod 32 -> conflict-free strided reads (stride 16 was a 32-way conflict, the
// R0 bottleneck: SQ_LDS_BANK_CONFLICT 1.09e8 ~= 64% of all CU cycles).

#define COLS 4096
#define KTOP 64u
#define NT 256
#define EPT 16   // elements per thread (COLS / NT)

__device__ __forceinline__ unsigned padidx(unsigned b) { return b + (b >> 4); }

__global__ __launch_bounds__(NT) void topk_mask_kernel(const float* __restrict__ x,
                                                       float* __restrict__ out) {
    const int row = blockIdx.x;
    const int t = threadIdx.x;
    const float* __restrict__ xr = x + (size_t)row * COLS;
    float* __restrict__ orow = out + (size_t)row * COLS;

    __shared__ unsigned hist[4096 + 256];           // padded: 4352 words = 17 KB
    __shared__ alignas(16) unsigned sc[NT];
    __shared__ alignas(16) unsigned sc2[NT];
    __shared__ unsigned sh_selbin;
    __shared__ unsigned sh_selS;

    // ---- Load 16 contiguous floats per thread; convert to sortable keys ----
    unsigned key[EPT];
    const float4* xv = reinterpret_cast<const float4*>(xr) + t * 4;
    #pragma unroll
    for (int c = 0; c < 4; ++c) {
        float4 v = xv[c];
        float f[4] = {v.x, v.y, v.z, v.w};
        #pragma unroll
        for (int j = 0; j < 4; ++j) {
            unsigned u = __float_as_uint(f[j]);
            key[4 * c + j] = (u & 0x80000000u) ? ~u : (u | 0x80000000u);
        }
    }

    unsigned need = KTOP;
    unsigned prefix = 0;   // accumulated selected high bits
    unsigned T = 0;        // final threshold key

    // ================= Pass 0: 4096 bins over key[31:20] =================
    {
        #pragma unroll
        for (int i = 0; i < 17; ++i) hist[t + NT * i] = 0u;
        __syncthreads();

        #pragma unroll
        for (int j = 0; j < EPT; ++j) atomicAdd(&hist[padidx(key[j] >> 20)], 1u);
        __syncthreads();

        // read own 16 bins ONCE into regs (base 17t: conflict-free)
        unsigned hr[16];
        unsigned L = 0;
        const unsigned base = 17u * t;
        #pragma unroll
        for (int i = 0; i < 16; ++i) { hr[i] = hist[base + i]; L += hr[i]; }
        sc[t] = L;
        __syncthreads();

        if (t < 64) {   // exclusive suffix scan of 256 partials, wave 0 only
            uint4 a = reinterpret_cast<const uint4*>(sc)[t];
            unsigned tot = a.x + a.y + a.z + a.w;
            unsigned suf = tot;
            #pragma unroll
            for (int d = 1; d < 64; d <<= 1) {
                unsigned o = __shfl_down(suf, d, 64);
                if (t + d < 64) suf += o;
            }
            unsigned s3 = suf - tot;
            unsigned s2 = s3 + a.w;
            unsigned s1 = s2 + a.z;
            unsigned s0 = s1 + a.y;
            reinterpret_cast<uint4*>(sc2)[t] = make_uint4(s0, s1, s2, s3);
        }
        __syncthreads();

        unsigned S = sc2[t];
        #pragma unroll
        for (int i = 15; i >= 0; --i) {
            unsigned h = hr[i];
            unsigned Sn = S + h;
            if (S < need && need <= Sn) { sh_selbin = 16u * t + i; sh_selS = S; }
            S = Sn;
        }
        __syncthreads();

        prefix = sh_selbin;       // 12-bit prefix
        need -= sh_selS;
        __syncthreads();          // all reads of sh_* done before next pass writes
    }

    // ============ Passes 1,2: 1024 bins over 10-bit digits ============
    #pragma unroll
    for (int pass = 1; pass <= 2; ++pass) {
        #pragma unroll
        for (int i = 0; i < 5; ++i) {
            unsigned idx = t + NT * i;
            if (idx < 1024 + 64) hist[idx] = 0u;
        }
        __syncthreads();

        const int pshift = (pass == 1) ? 20 : 10;   // bits above current digit
        const int dshift = (pass == 1) ? 10 : 0;
        #pragma unroll
        for (int j = 0; j < EPT; ++j) {
            unsigned k = key[j];
            if ((k >> pshift) == prefix)
                atomicAdd(&hist[padidx((k >> dshift) & 0x3FFu)], 1u);
        }
        __syncthreads();

        unsigned hr[4];
        unsigned L = 0;
        const unsigned base = 4u * t + (t >> 2);   // padidx(4t+i) for i<4
        #pragma unroll
        for (int i = 0; i < 4; ++i) { hr[i] = hist[base + i]; L += hr[i]; }
        sc[t] = L;
        __syncthreads();

        if (t < 64) {
            uint4 a = reinterpret_cast<const uint4*>(sc)[t];
            unsigned tot = a.x + a.y + a.z + a.w;
            unsigned suf = tot;
            #pragma unroll
            for (int d = 1; d < 64; d <<= 1) {
                unsigned o = __shfl_down(suf, d, 64);
                if (t + d < 64) suf += o;
            }
            unsigned s3 = suf - tot;
            unsigned s2 = s3 + a.w;
            unsigned s1 = s2 + a.z;
            unsigned s0 = s1 + a.y;
            reinterpret_cast<uint4*>(sc2)[t] = make_uint4(s0, s1, s2, s3);
        }
        __syncthreads();

        unsigned S = sc2[t];
        #pragma unroll
        for (int i = 3; i >= 0; --i) {
            unsigned h = hr[i];
            unsigned Sn = S + h;
            if (S < need && need <= Sn) { sh_selbin = 4u * t + i; sh_selS = S; }
            S = Sn;
        }
        __syncthreads();

        unsigned b = sh_selbin;
        need -= sh_selS;
        prefix = (prefix << 10) | b;   // after pass 2 this is the full 32-bit key
        __syncthreads();
    }
    T = prefix;

    // ---- Stable rank among key==T elements, ascending index order ----
    unsigned eq = 0;
    #pragma unroll
    for (int j = 0; j < EPT; ++j) eq += (key[j] == T) ? 1u : 0u;
    sc[t] = eq;
    __syncthreads();
    if (t < 64) {   // exclusive prefix scan
        uint4 a = reinterpret_cast<const uint4*>(sc)[t];
        unsigned tot = a.x + a.y + a.z + a.w;
        unsigned pre = tot;
        #pragma unroll
        for (int d = 1; d < 64; d <<= 1) {
            unsigned o = __shfl_up(pre, d, 64);
            if (t >= d) pre += o;
        }
        unsigned p0 = pre - tot;
        unsigned p1 = p0 + a.x;
        unsigned p2 = p1 + a.y;
        unsigned p3 = p2 + a.z;
        reinterpret_cast<uint4*>(sc2)[t] = make_uint4(p0, p1, p2, p3);
    }
    __syncthreads();

    // ---- Output: keep key>T always; key==T only for the first `need` by index ----
    unsigned rank = sc2[t];
    float4* ov = reinterpret_cast<float4*>(orow) + t * 4;
    #pragma unroll
    for (int c = 0; c < 4; ++c) {
        float r[4];
        #pragma unroll
        for (int j = 0; j < 4; ++j) {
            unsigned k = key[4 * c + j];
            bool inc;
            if (k > T)       inc = true;
            else if (k == T) { inc = (rank < need); rank += 1u; }
            else             inc = false;
            unsigned u = (k & 0x80000000u) ? (k ^ 0x80000000u) : ~k;
            r[j] = inc ? __uint_as_float(u) : 0.0f;
        }
        float4 o4;
        o4.x = r[0]; o4.y = r[1]; o4.z = r[2]; o4.w = r[3];
        ov[c] = o4;
    }
}

extern "C" void kernel_launch(void* const* d_in, const int* in_sizes, int n_in,
                              void* d_out, int out_size, void* d_ws, size_t ws_size,
                              hipStream_t stream) {
    const float* x = (const float*)d_in[0];
    float* out = (float*)d_out;
    const int rows = in_sizes[0] / COLS;  // 16384
    topk_mask_kernel<<<rows, NT, 0, stream>>>(x, out);
}